// Round 13
// baseline (786.803 us; speedup 1.0000x reference)
//
#include <hip/hip_runtime.h>
#include <hip/hip_bf16.h>
#include <hip/hip_cooperative_groups.h>
#include <math.h>

namespace cg = cooperative_groups;

// Problem constants
#define B 32
#define N 128
#define BT (B*N)          // 4096
#define WD 100
#define UD 25
#define D 125             // LSTM hidden per direction
#define G4 (4*D)          // 500 gates
#define H2 (2*D)          // 250
#define HID 100
#define L 50
#define MT 16

__device__ __forceinline__ float fast_tanh(float x) {
    float e = __expf(2.0f * x);
    return 1.0f - 2.0f / (e + 1.0f);
}
__device__ __forceinline__ float fast_sigmoid(float x) {
    return 1.0f / (1.0f + __expf(-x));
}
__device__ __forceinline__ float bcast_lane(float v, int k) {
    return __builtin_bit_cast(float, __builtin_amdgcn_readlane(__builtin_bit_cast(int, v), k));
}

#define REP64(X) \
 X(0) X(1) X(2) X(3) X(4) X(5) X(6) X(7) X(8) X(9) \
 X(10) X(11) X(12) X(13) X(14) X(15) X(16) X(17) X(18) X(19) \
 X(20) X(21) X(22) X(23) X(24) X(25) X(26) X(27) X(28) X(29) \
 X(30) X(31) X(32) X(33) X(34) X(35) X(36) X(37) X(38) X(39) \
 X(40) X(41) X(42) X(43) X(44) X(45) X(46) X(47) X(48) X(49) \
 X(50) X(51) X(52) X(53) X(54) X(55) X(56) X(57) X(58) X(59) \
 X(60) X(61) X(62) X(63)

struct TJob { const float* src; float* dst; int R, C, ldo, coff; };

struct KArgs {
    const int *wids, *uids, *tarcs;
    const float *wl, *tl;
    const float *l0f_b, *l0b_b, *l1f_b, *l1b_b, *eh_b, *em_b, *lm_b, *lh_b;
    const float *esW, *esb, *lsW, *lsb;
    TJob j[12];
    float *A, *words, *C, *WT_l0, *WT_l1, *WT_s3, *WT_lh;
    float *WhT_l0f, *WhT_l0b, *WhT_l1f, *WhT_l1b;
    float *b_l0, *b_l1, *b_s3, *rel_head;
    float *trees, *preds, *arc, *rel;
};

// ---------------------------------------------------------------------------
// proj helpers (barrier-free)
// ---------------------------------------------------------------------------
__device__ __forceinline__
void proj_stage(int tid, int nthr, const float* __restrict__ x, int K, int ldx,
                const int* __restrict__ gather_idx, int m0, float* xs) {
    for (int e = tid; e < MT * K; e += nthr) {
        int r = e / K, k = e - r * K;
        int m = m0 + r;
        int row = m;
        if (gather_idx) {
            int bb = m >> 7, np = m & 127;
            row = (bb << 7) + (np == 0 ? 0 : gather_idx[m]);
        }
        xs[k*17 + r] = x[(size_t)row*ldx + k];
    }
}

template<int CPT, int BD>
__device__ __forceinline__
void proj_compute(int tid, const float* xs, const float* __restrict__ WT,
                  const float* __restrict__ bias, float* __restrict__ out,
                  int Ncols, int K, int m0) {
    int lane = tid & 63;
    float acc[CPT][MT];
    int ncl[CPT];
    #pragma unroll
    for (int j = 0; j < CPT; j++) {
        int n = tid + j*BD;
        ncl[j] = (n < Ncols) ? n : (Ncols - 1);
        #pragma unroll
        for (int r = 0; r < MT; r++) acc[j][r] = 0.0f;
    }
    float wkc[4][CPT];
    #pragma unroll
    for (int q = 0; q < 4; q++)
        #pragma unroll
        for (int j = 0; j < CPT; j++)
            wkc[q][j] = WT[(size_t)q*Ncols + ncl[j]];
    int k0 = 0;
    for (; k0 + 8 <= K; k0 += 4) {
        float xv = xs[(k0 + (lane >> 4))*17 + (lane & 15)];
        float wkn[4][CPT];
        #pragma unroll
        for (int q = 0; q < 4; q++)
            #pragma unroll
            for (int j = 0; j < CPT; j++)
                wkn[q][j] = WT[(size_t)(k0 + 4 + q)*Ncols + ncl[j]];
        #pragma unroll
        for (int q = 0; q < 4; q++) {
            #pragma unroll
            for (int r = 0; r < 16; r++) {
                float hv = bcast_lane(xv, q*16 + r);
                #pragma unroll
                for (int j = 0; j < CPT; j++)
                    acc[j][r] = fmaf(wkc[q][j], hv, acc[j][r]);
            }
        }
        #pragma unroll
        for (int q = 0; q < 4; q++)
            #pragma unroll
            for (int j = 0; j < CPT; j++)
                wkc[q][j] = wkn[q][j];
    }
    { // last full group
        float xv = xs[(k0 + (lane >> 4))*17 + (lane & 15)];
        #pragma unroll
        for (int q = 0; q < 4; q++) {
            #pragma unroll
            for (int r = 0; r < 16; r++) {
                float hv = bcast_lane(xv, q*16 + r);
                #pragma unroll
                for (int j = 0; j < CPT; j++)
                    acc[j][r] = fmaf(wkc[q][j], hv, acc[j][r]);
            }
        }
        k0 += 4;
    }
    for (; k0 < K; k0++) {
        float xv = xs[k0*17 + (lane & 15)];
        float wk[CPT];
        #pragma unroll
        for (int j = 0; j < CPT; j++) wk[j] = WT[(size_t)k0*Ncols + ncl[j]];
        #pragma unroll
        for (int r = 0; r < 16; r++) {
            float hv = bcast_lane(xv, r);
            #pragma unroll
            for (int j = 0; j < CPT; j++)
                acc[j][r] = fmaf(wk[j], hv, acc[j][r]);
        }
    }
    #pragma unroll
    for (int j = 0; j < CPT; j++) {
        int n = tid + j*BD;
        if (n < Ncols) {
            float bb = bias[n];
            #pragma unroll
            for (int r = 0; r < MT; r++) out[(size_t)(m0 + r)*Ncols + n] = acc[j][r] + bb;
        }
    }
}

// ---------------------------------------------------------------------------
// scan body — round-8 structure verbatim (best measured: 137 us)
// ---------------------------------------------------------------------------
__device__ __forceinline__
void scan_body(int blk, const float* __restrict__ xgc,
               const float* __restrict__ WhTf, const float* __restrict__ WhTb,
               float* __restrict__ out, float* hbuf, float* pbuf) {
    int dir = blk & 1;
    int b = blk >> 1;
    const float* WhT = dir ? WhTb : WhTf;
    int off = dir ? D : 0;
    int t = threadIdx.x;
    int g = t & 511;
    int half = t >> 9;
    int kbase = half << 6;

    unsigned voff0 = ((unsigned)kbase * 500u + (unsigned)g) * 4u;
#define DECLW(i) float w##i; \
    asm volatile("global_load_dword %0, %1, %2" \
                 : "=v"(w##i) : "v"(voff0 + (unsigned)(i)*2000u), "s"(WhT));
    REP64(DECLW)
#undef DECLW
    asm volatile("s_waitcnt vmcnt(0)" ::: "memory");

    float c = 0.0f;
    if (t < 128) hbuf[t] = 0.0f;
    __syncthreads();

    const float* xb = xgc + (size_t)b * N * 1000 + dir * 500;
    bool xa = (half == 0) && (g < G4);
    float x_next = xa ? xb[(size_t)(dir ? (N-1) : 0) * 1000 + g] : 0.0f;

    const float4* h4q = ((const float4*)hbuf) + (kbase >> 2);

#define FMA4(q, i0, i1, i2, i3) { float4 hv = h4q[q]; \
    a4[0] = fmaf(w##i0, hv.x, a4[0]); \
    a4[1] = fmaf(w##i1, hv.y, a4[1]); \
    a4[2] = fmaf(w##i2, hv.z, a4[2]); \
    a4[3] = fmaf(w##i3, hv.w, a4[3]); }

    for (int ti = 0; ti < N; ti++) {
        int tt = dir ? (N-1-ti) : ti;
        float x_cur = x_next;
        float xn = 0.0f;
        if (xa && ti + 1 < N)
            xn = xb[(size_t)(dir ? (tt-1) : (tt+1)) * 1000 + g];
        float a4[4];
        a4[0] = x_cur; a4[1] = 0.0f; a4[2] = 0.0f; a4[3] = 0.0f;
        FMA4(0,  0,  1,  2,  3)  FMA4(1,  4,  5,  6,  7)
        FMA4(2,  8,  9, 10, 11)  FMA4(3, 12, 13, 14, 15)
        FMA4(4, 16, 17, 18, 19)  FMA4(5, 20, 21, 22, 23)
        FMA4(6, 24, 25, 26, 27)  FMA4(7, 28, 29, 30, 31)
        FMA4(8, 32, 33, 34, 35)  FMA4(9, 36, 37, 38, 39)
        FMA4(10, 40, 41, 42, 43) FMA4(11, 44, 45, 46, 47)
        FMA4(12, 48, 49, 50, 51) FMA4(13, 52, 53, 54, 55)
        FMA4(14, 56, 57, 58, 59) FMA4(15, 60, 61, 62, 63)
        x_next = xn;
        pbuf[t] = (a4[0] + a4[1]) + (a4[2] + a4[3]);
        __syncthreads();
        if (t < D) {
            float iv = pbuf[t]       + pbuf[512 + t];
            float fv = pbuf[D+t]     + pbuf[512 + D+t];
            float gv = pbuf[2*D+t]   + pbuf[512 + 2*D+t];
            float ov = pbuf[3*D+t]   + pbuf[512 + 3*D+t];
            float si = fast_sigmoid(iv);
            float sf = fast_sigmoid(fv);
            float so = fast_sigmoid(ov);
            c = sf * c + si * fast_tanh(gv);
            float h = so * fast_tanh(c);
            hbuf[t] = h;
            out[(size_t)(b*N + tt)*H2 + off + t] = h;
        }
        __syncthreads();
    }
#undef FMA4
}

// wave-level argmax combine: (v,i) keeps max with lowest index on ties
__device__ __forceinline__ void amax_step(float& v, int& i, float vo, int io) {
    if (vo > v || (vo == v && io < i)) { v = vo; i = io; }
}

// ---------------------------------------------------------------------------
// THE mega-kernel: 256 blocks x 1024 threads, cooperative.
// ---------------------------------------------------------------------------
__global__ __launch_bounds__(1024)
void mega_kernel(KArgs a) {
    cg::grid_group grid = cg::this_grid();
    __shared__ __align__(16) float smem[14720];   // 58,880 B
    int tid = threadIdx.x;
    int blk = blockIdx.x;
    size_t gstride = (size_t)gridDim.x * blockDim.x;
    size_t gtid = (size_t)blk * blockDim.x + tid;

    // ---------------- P0: setup (transposes, embed, biases, pads) ----------
    for (int ji = 0; ji < 12; ji++) {
        TJob jb = a.j[ji];
        int tot = jb.R * jb.C;
        for (size_t e = gtid; e < (size_t)tot; e += gstride) {
            int n = (int)(e / jb.C), k = (int)(e - (size_t)n*jb.C);
            jb.dst[(size_t)k*jb.ldo + jb.coff + n] = jb.src[e];
        }
    }
    for (size_t e = gtid; e < (size_t)BT*D; e += gstride) {
        int bt = (int)(e / D), t = (int)(e - (size_t)bt*D);
        a.words[e] = (t < WD) ? a.wl[(size_t)a.wids[bt]*WD + t]
                              : a.tl[(size_t)a.uids[bt]*UD + (t - WD)];
    }
    for (size_t e = gtid; e < 2300; e += gstride) {
        int t = (int)e;
        if (t < 500)        a.b_l0[t] = a.l0f_b[t];
        else if (t < 1000)  a.b_l0[t] = a.l0b_b[t-500];
        else if (t < 1500)  a.b_l1[t-1000] = a.l1f_b[t-1000];
        else if (t < 2000)  a.b_l1[t-1000] = a.l1b_b[t-1500];
        else if (t < 2100)  a.b_s3[t-2000] = a.eh_b[t-2000];
        else if (t < 2200)  a.b_s3[t-2000] = a.em_b[t-2100];
        else                a.b_s3[t-2000] = a.lm_b[t-2200];
    }
    for (size_t e = gtid; e < 4*1516; e += gstride) {
        int m = (int)(e / 1516), o = (int)(e % 1516);
        float* p = (m == 0) ? a.WhT_l0f : (m == 1) ? a.WhT_l0b
                 : (m == 2) ? a.WhT_l1f : a.WhT_l1b;
        p[125*500 + o] = 0.0f;
    }
    grid.sync();

    // ---------------- P1: proj layer-0 (K=125, N=1000) ----------------------
    {
        int m0 = blk * MT;
        proj_stage(tid, 1024, a.words, D, D, nullptr, m0, smem);
        __syncthreads();
        if (tid < 512)
            proj_compute<2, 512>(tid, smem, a.WT_l0, a.b_l0, a.A, 1000, D, m0);
    }
    grid.sync();

    // ---------------- P2: scan layer-0 -> C ---------------------------------
    if (blk < 64) scan_body(blk, a.A, a.WhT_l0f, a.WhT_l0b, a.C, smem, smem + 128);
    grid.sync();

    // ---------------- P3: proj layer-1 (K=250, N=1000) ----------------------
    {
        int m0 = blk * MT;
        proj_stage(tid, 1024, a.C, H2, H2, nullptr, m0, smem);
        __syncthreads();
        if (tid < 512)
            proj_compute<2, 512>(tid, smem, a.WT_l1, a.b_l1, a.A, 1000, H2, m0);
    }
    grid.sync();

    // ---------------- P4: scan layer-1 -> C ---------------------------------
    if (blk < 64) scan_body(blk, a.A, a.WhT_l1f, a.WhT_l1b, a.C, smem, smem + 128);
    grid.sync();

    // ---------------- P5: scorer projections (s3: N=300; lh gathered: N=100) -
    {
        int m0 = blk * MT;
        float* xs1 = smem;
        float* xs2 = smem + 4272;
        if (tid < 512) proj_stage(tid, 512, a.C, H2, H2, nullptr, m0, xs1);
        else           proj_stage(tid - 512, 512, a.C, H2, H2, a.tarcs, m0, xs2);
        __syncthreads();
        if (tid < 512) {
            if ((tid & ~63) < 300)
                proj_compute<1, 512>(tid, xs1, a.WT_s3, a.b_s3, a.A, 300, H2, m0);
        } else {
            int t2 = tid - 512;
            if ((t2 & ~63) < 100)
                proj_compute<1, 512>(t2, xs2, a.WT_lh, a.lh_b, a.rel_head, 100, H2, m0);
        }
    }
    grid.sync();

    // ---------------- P6: arc scores + argmax, then rel ---------------------
    {
        float* wms  = smem;              // [128*101] = 12928
        float* whs  = smem + 12928;      // [16*100]  = 1600
        float* es   = smem + 14528;      // [100]
        float* redv = smem + 14628;      // [16]
        int*   redi = (int*)(smem + 14644); // [16]

        int b = blk >> 3;
        int ig0 = (blk & 7) * 16;
        for (int e = tid; e < 128 * HID; e += 1024) {
            int r = e / HID, h = e - r * HID;
            wms[r*101 + h] = a.A[(size_t)(b*N + r)*300 + 100 + h];
        }
        for (int e = tid; e < 16 * HID; e += 1024) {
            int ii = e / HID, h = e - ii * HID;
            whs[e] = a.A[(size_t)(b*N + ig0 + ii)*300 + h];
        }
        if (tid < HID) es[tid] = a.esW[tid];
        __syncthreads();

        float eb = a.esb[0];
        int j = tid & 127;
        int sub = tid >> 7;              // 8 subgroups of 128 (2 waves each)
        const float* wmr = &wms[j * 101];
        for (int iter = 0; iter < 2; iter++) {
            int ii = sub + iter*8;
            int i = ig0 + ii;
            int bi = b * N + i;
            float acc = 0.0f;
            const float* whr = &whs[ii * HID];
            for (int h = 0; h < HID; h++)
                acc = fmaf(es[h], fast_tanh(whr[h] + wmr[h]), acc);
            int tai = (i == 0) ? 0 : a.tarcs[bi];
            float score = acc + eb + 1.0f - ((j == tai) ? 1.0f : 0.0f);
            a.arc[(size_t)bi*N + j] = score;
            // wave-level argmax (64 lanes), then cross-wave via LDS
            float v = score; int vi = j;
            #pragma unroll
            for (int off = 32; off; off >>= 1)
                amax_step(v, vi, __shfl_down(v, off), __shfl_down(vi, off));
            if ((tid & 63) == 0) {
                int w = tid >> 6;        // 16 waves; sub = w>>1
                redv[w] = v; redi[w] = vi;
            }
            __syncthreads();
            if (j == 0) {
                float v0 = redv[sub*2], v1 = redv[sub*2+1];
                int  i0 = redi[sub*2], i1 = redi[sub*2+1];
                amax_step(v0, i0, v1, i1);
                a.trees[bi] = (float)i0;
            }
            __syncthreads();
        }

        // ---- rel: 16 bt per block, one 64-thread group per bt ----
        __syncthreads();
        int grp = tid >> 6, t = tid & 63;
        int bt = blk * 16 + grp;
        float* tv = smem + grp * 104;    // reuse wms region
        for (int h = t; h < HID; h += 64)
            tv[h] = fast_tanh(a.A[(size_t)bt*300 + 200 + h] + a.rel_head[(size_t)bt*HID + h]);
        __syncthreads();
        float score = -1e30f;
        if (t < L) {
            float acc = 0.0f;
            const float* wrow = a.lsW + t*HID;
            for (int h = 0; h < HID; h++) acc = fmaf(wrow[h], tv[h], acc);
            score = acc + a.lsb[t];
            a.rel[(size_t)bt*L + t] = score;
        }
        float v = score; int vi = t;
        #pragma unroll
        for (int off = 32; off; off >>= 1)
            amax_step(v, vi, __shfl_down(v, off), __shfl_down(vi, off));
        if (t == 0) a.preds[bt] = (float)vi;
    }
}

// ---------------------------------------------------------------------------
extern "C" void kernel_launch(void* const* d_in, const int* in_sizes, int n_in,
                              void* d_out, int out_size, void* d_ws, size_t ws_size,
                              hipStream_t stream) {
    const int*   word_ids    = (const int*)  d_in[0];
    const int*   upos_ids    = (const int*)  d_in[1];
    const int*   target_arcs = (const int*)  d_in[2];
    const float* wlookup     = (const float*)d_in[3];
    const float* tlookup     = (const float*)d_in[4];
    const float* l0f_Wih = (const float*)d_in[5];
    const float* l0f_Whh = (const float*)d_in[6];
    const float* l0f_b   = (const float*)d_in[7];
    const float* l0b_Wih = (const float*)d_in[8];
    const float* l0b_Whh = (const float*)d_in[9];
    const float* l0b_b   = (const float*)d_in[10];
    const float* l1f_Wih = (const float*)d_in[11];
    const float* l1f_Whh = (const float*)d_in[12];
    const float* l1f_b   = (const float*)d_in[13];
    const float* l1b_Wih = (const float*)d_in[14];
    const float* l1b_Whh = (const float*)d_in[15];
    const float* l1b_b   = (const float*)d_in[16];
    const float* eh_W = (const float*)d_in[17];
    const float* eh_b = (const float*)d_in[18];
    const float* em_W = (const float*)d_in[19];
    const float* em_b = (const float*)d_in[20];
    const float* es_W = (const float*)d_in[21];
    const float* es_b = (const float*)d_in[22];
    const float* lh_W = (const float*)d_in[23];
    const float* lh_b = (const float*)d_in[24];
    const float* lm_W = (const float*)d_in[25];
    const float* lm_b = (const float*)d_in[26];
    const float* ls_W = (const float*)d_in[27];
    const float* ls_b = (const float*)d_in[28];

    float* out = (float*)d_out;
    float* ws = (float*)d_ws;

    KArgs ka{};
    ka.wids = word_ids; ka.uids = upos_ids; ka.tarcs = target_arcs;
    ka.wl = wlookup; ka.tl = tlookup;
    ka.l0f_b = l0f_b; ka.l0b_b = l0b_b; ka.l1f_b = l1f_b; ka.l1b_b = l1b_b;
    ka.eh_b = eh_b; ka.em_b = em_b; ka.lm_b = lm_b; ka.lh_b = lh_b;
    ka.esW = es_W; ka.esb = es_b; ka.lsW = ls_W; ka.lsb = ls_b;

    ka.A       = ws;                    // 4,096,000
    ka.words   = ws + 4096000;          //   512,000
    ka.C       = ws + 4608000;          // 1,024,000
    ka.WT_l0   = ws + 5632000;          //   125,000
    ka.WT_l1   = ws + 5757000;          //   250,000
    ka.WT_s3   = ws + 6007000;          //    75,000
    ka.WT_lh   = ws + 6082000;          //    25,000
    ka.WhT_l0f = ws + 6107000;          //    64,016
    ka.WhT_l0b = ws + 6171016;
    ka.WhT_l1f = ws + 6235032;
    ka.WhT_l1b = ws + 6299048;
    ka.b_l0    = ws + 6363064;
    ka.b_l1    = ws + 6364064;
    ka.b_s3    = ws + 6365064;
    ka.rel_head = ws + 6366064;         //   409,600

    ka.trees = out;
    ka.preds = out + BT;
    ka.arc   = out + 2*BT;
    ka.rel   = out + 2*BT + BT*N;

    TJob js[12] = {
        { l0f_Wih, ka.WT_l0, 500, 125, 1000, 0 },
        { l0b_Wih, ka.WT_l0, 500, 125, 1000, 500 },
        { l1f_Wih, ka.WT_l1, 500, 250, 1000, 0 },
        { l1b_Wih, ka.WT_l1, 500, 250, 1000, 500 },
        { eh_W, ka.WT_s3, 100, 250, 300, 0 },
        { em_W, ka.WT_s3, 100, 250, 300, 100 },
        { lm_W, ka.WT_s3, 100, 250, 300, 200 },
        { lh_W, ka.WT_lh, 100, 250, 100, 0 },
        { l0f_Whh, ka.WhT_l0f, 500, 125, 500, 0 },
        { l0b_Whh, ka.WhT_l0b, 500, 125, 500, 0 },
        { l1f_Whh, ka.WhT_l1f, 500, 125, 500, 0 },
        { l1b_Whh, ka.WhT_l1b, 500, 125, 500, 0 },
    };
    for (int i = 0; i < 12; i++) ka.j[i] = js[i];

    void* params[] = { &ka };
    hipLaunchCooperativeKernel((const void*)mega_kernel, dim3(256), dim3(1024),
                               params, 0, stream);
}